// Round 6
// baseline (159.717 us; speedup 1.0000x reference)
//
#include <hip/hip_runtime.h>
#include <hip/hip_fp16.h>
#include <math.h>

// SDF loss: out = [loss(1), sdf_values(B*N), se3(B*16)]  (float32)
// G fixed at 256: flat grid index = (x<<16)|(y<<8)|z.
// u clamped to <= 254.9999 so x0,y0,z0 <= 254; min(i0+1,255) never binds.
//
// ws layout: [0,4KB) rt | [128KB, +127.5MB) z-plane table
// Z-plane table: entry e(x,y,z) = fp16x4 xy-cell corners in plane z:
//   .x = half2( g(x,y,z),   g(x+1,y,z)   )
//   .y = half2( g(x,y+1,z), g(x+1,y+1,z) )
// Sample reads entries z0,z0+1 (16 contiguous B, same 64B line 7/8 of time).
// sdf kernel: 4 poses/thread (MLP), NT store for sdf_out (keep L3 for table),
// loss via one atomicAdd per block (out[0] zeroed by pack_pose).

__device__ __forceinline__ void pose_math(const float* __restrict__ pose_delta,
                                          const float* __restrict__ pose_init,
                                          float* __restrict__ out,
                                          float* __restrict__ rt,
                                          int b, long long se3_off)
{
    const float* d = pose_delta + b * 6;
    float ux = d[0], uy = d[1], uz = d[2];
    float wx = d[3], wy = d[4], wz = d[5];
    float th2 = wx*wx + wy*wy + wz*wz;
    float th  = sqrtf(th2);
    float A, Bc, Cc;
    if (th < 1e-6f) {
        A  = 1.0f - th2 * (1.0f/6.0f);
        Bc = 0.5f - th2 * (1.0f/24.0f);
        Cc = (1.0f/6.0f) - th2 * (1.0f/120.0f);
    } else {
        float sn = sinf(th), cs = cosf(th);
        A  = sn / th;
        Bc = (1.0f - cs) / th2;
        Cc = (th - sn) / (th2 * th);
    }
    float K[3][3]  = {{0.f,-wz,wy},{wz,0.f,-wx},{-wy,wx,0.f}};
    float K2[3][3];
    #pragma unroll
    for (int i = 0; i < 3; i++)
        #pragma unroll
        for (int j = 0; j < 3; j++) {
            float s = 0.f;
            #pragma unroll
            for (int k = 0; k < 3; k++) s += K[i][k] * K[k][j];
            K2[i][j] = s;
        }
    float R[3][3], V[3][3];
    #pragma unroll
    for (int i = 0; i < 3; i++)
        #pragma unroll
        for (int j = 0; j < 3; j++) {
            float I = (i == j) ? 1.f : 0.f;
            R[i][j] = I + A  * K[i][j] + Bc * K2[i][j];
            V[i][j] = I + Bc * K[i][j] + Cc * K2[i][j];
        }
    float tt[3];
    #pragma unroll
    for (int i = 0; i < 3; i++)
        tt[i] = V[i][0]*ux + V[i][1]*uy + V[i][2]*uz;

    const float* P = pose_init + b * 16;
    float M[3][4];
    #pragma unroll
    for (int i = 0; i < 3; i++)
        #pragma unroll
        for (int j = 0; j < 4; j++)
            M[i][j] = R[i][0]*P[0*4+j] + R[i][1]*P[1*4+j] + R[i][2]*P[2*4+j] + tt[i]*P[3*4+j];

    float* o = out + se3_off + (long long)b * 16;
    #pragma unroll
    for (int i = 0; i < 3; i++)
        #pragma unroll
        for (int j = 0; j < 4; j++) o[i*4+j] = M[i][j];
    o[12] = P[12]; o[13] = P[13]; o[14] = P[14]; o[15] = P[15];

    float* r = rt + b * 12;
    #pragma unroll
    for (int i = 0; i < 3; i++) {
        r[i*4+0] = M[i][0]; r[i*4+1] = M[i][1];
        r[i*4+2] = M[i][2]; r[i*4+3] = M[i][3];
    }
}

// Fused: z-plane table pack (all blocks) + pose math + loss zero (block 0).
__global__ __launch_bounds__(256)
void pack_pose(const float* __restrict__ g, uint2* __restrict__ tbl,
               const float* __restrict__ pose_delta,
               const float* __restrict__ pose_init,
               float* __restrict__ out, float* __restrict__ rt,
               int B, long long se3_off)
{
    int idx = blockIdx.x * 256 + threadIdx.x;   // x = idx>>16 in [0,254]
    int y = (idx >> 8) & 255;
    int ys = (y < 255) ? 256 : 0;               // y=255 entries never read; avoid OOB
    const float* p = g + idx;                   // x+1 <= 255 always (x <= 254)
    float e00 = p[0],          e10 = p[65536];
    float e01 = p[ys],         e11 = p[65536 + ys];
    uint2 u;
    __half2 h;
    h = __floats2half2_rn(e00, e10); u.x = *(unsigned int*)&h;
    h = __floats2half2_rn(e01, e11); u.y = *(unsigned int*)&h;
    tbl[idx] = u;

    if (blockIdx.x == 0) {
        if (threadIdx.x == 0) out[0] = 0.0f;
        if ((int)threadIdx.x < B)
            pose_math(pose_delta, pose_init, out, rt, threadIdx.x, se3_off);
    }
}

// 4 poses per thread; per sample two 8B loads (z0, z0+1). NT store for output;
// per-block loss atomicAdd.
__global__ __launch_bounds__(256)
void sdf_zp4(const uint2* __restrict__ tbl,
             const float* __restrict__ limits,
             const float* __restrict__ points,
             const float* __restrict__ rt,
             float* __restrict__ sdf_out,     // out+1
             float* __restrict__ loss,        // out
             int N, int B)
{
    const int bg = blockIdx.y;       // pose group
    const int b0 = bg * 4;
    const int n  = blockIdx.x * 256 + threadIdx.x;

    float M[4][12];
    #pragma unroll
    for (int bb = 0; bb < 4; bb++) {
        int b = min(b0 + bb, B - 1);
        const float* m = rt + b * 12;
        #pragma unroll
        for (int j = 0; j < 12; j++) M[bb][j] = m[j];
    }
    float lo0=limits[0], lo1=limits[1], lo2=limits[2];
    float hi0=limits[3], hi1=limits[4], hi2=limits[5];
    float s0 = 255.0f/(hi0-lo0), s1 = 255.0f/(hi1-lo1), s2 = 255.0f/(hi2-lo2);

    float val = 0.0f;
    if (n < N) {
        float px = points[n*3+0], py = points[n*3+1], pz = points[n*3+2];

        int   idx[4];
        float fx[4], fy[4], fz[4];
        #pragma unroll
        for (int bb = 0; bb < 4; bb++) {
            float x = M[bb][0]*px + M[bb][1]*py + M[bb][2]*pz  + M[bb][3];
            float y = M[bb][4]*px + M[bb][5]*py + M[bb][6]*pz  + M[bb][7];
            float z = M[bb][8]*px + M[bb][9]*py + M[bb][10]*pz + M[bb][11];
            float u0 = fminf(fmaxf((x - lo0) * s0, 0.f), 254.9999f);
            float u1 = fminf(fmaxf((y - lo1) * s1, 0.f), 254.9999f);
            float u2 = fminf(fmaxf((z - lo2) * s2, 0.f), 254.9999f);
            int x0 = (int)u0, y0 = (int)u1, z0 = (int)u2;
            fx[bb] = u0 - (float)x0;
            fy[bb] = u1 - (float)y0;
            fz[bb] = u2 - (float)z0;
            idx[bb] = (x0 << 16) | (y0 << 8) | z0;
        }

        // 8 independent 8B gathers (4 line-pairs) in flight
        uint2 e0[4], e1[4];
        #pragma unroll
        for (int bb = 0; bb < 4; bb++) {
            e0[bb] = tbl[idx[bb]];
            e1[bb] = tbl[idx[bb] + 1];
        }

        #pragma unroll
        for (int bb = 0; bb < 4; bb++) {
            float2 a00 = __half22float2(*(__half2*)&e0[bb].x);  // (e00,e10) @ z0
            float2 a01 = __half22float2(*(__half2*)&e0[bb].y);  // (e01,e11) @ z0
            float2 b00 = __half22float2(*(__half2*)&e1[bb].x);  // @ z1
            float2 b01 = __half22float2(*(__half2*)&e1[bb].y);
            float c0 = a00.x + (a00.y - a00.x) * fx[bb];
            float c1 = a01.x + (a01.y - a01.x) * fx[bb];
            float p0 = c0 + (c1 - c0) * fy[bb];                 // plane z0
            float d0 = b00.x + (b00.y - b00.x) * fx[bb];
            float d1 = b01.x + (b01.y - b01.x) * fx[bb];
            float p1 = d0 + (d1 - d0) * fy[bb];                 // plane z1
            float v  = p0 + (p1 - p0) * fz[bb];
            if (b0 + bb < B) {
                __builtin_nontemporal_store(v, &sdf_out[(size_t)(b0 + bb) * N + n]);
                val += v * v;
            }
        }
    }

    #pragma unroll
    for (int off = 32; off > 0; off >>= 1) val += __shfl_down(val, off, 64);
    __shared__ float sm[4];
    int lane = threadIdx.x & 63, wid = threadIdx.x >> 6;
    if (lane == 0) sm[wid] = val;
    __syncthreads();
    if (threadIdx.x == 0)
        atomicAdd(loss, 0.5f * (sm[0] + sm[1] + sm[2] + sm[3]));
}

// ---------------- Fallback path (non-256 grid or tiny ws) ----------------
__global__ void pose_kernel(const float* __restrict__ pose_delta,
                            const float* __restrict__ pose_init,
                            float* __restrict__ out,
                            float* __restrict__ rt,
                            int B, long long se3_off)
{
    int b = blockIdx.x * blockDim.x + threadIdx.x;
    if (b == 0) out[0] = 0.0f;
    if (b >= B) return;
    pose_math(pose_delta, pose_init, out, rt, b, se3_off);
}

__global__ __launch_bounds__(256)
void sdf_kernel(const float* __restrict__ grid,
                const float* __restrict__ limits,
                const float* __restrict__ points,
                const float* __restrict__ rt,
                float* __restrict__ out, int N)
{
    const int b = blockIdx.y;
    const int n = blockIdx.x * 256 + threadIdx.x;
    const float* m = rt + b * 12;
    float m00=m[0], m01=m[1], m02=m[2],  m03=m[3];
    float m10=m[4], m11=m[5], m12=m[6],  m13=m[7];
    float m20=m[8], m21=m[9], m22=m[10], m23=m[11];
    float lo0=limits[0], lo1=limits[1], lo2=limits[2];
    float hi0=limits[3], hi1=limits[4], hi2=limits[5];
    float s0 = 255.0f/(hi0-lo0), s1 = 255.0f/(hi1-lo1), s2 = 255.0f/(hi2-lo2);

    float val = 0.0f;
    if (n < N) {
        float px = points[n*3+0], py = points[n*3+1], pz = points[n*3+2];
        float x = m00*px + m01*py + m02*pz + m03;
        float y = m10*px + m11*py + m12*pz + m13;
        float z = m20*px + m21*py + m22*pz + m23;
        float u0 = fminf(fmaxf((x - lo0) * s0, 0.f), 254.9999f);
        float u1 = fminf(fmaxf((y - lo1) * s1, 0.f), 254.9999f);
        float u2 = fminf(fmaxf((z - lo2) * s2, 0.f), 254.9999f);
        int x0 = (int)u0, y0 = (int)u1, z0 = (int)u2;
        float fx = u0 - (float)x0, fy = u1 - (float)y0, fz = u2 - (float)z0;
        int x1 = x0 + 1, y1 = y0 + 1, z1 = z0 + 1;
        int bx0 = x0 << 16, bx1 = x1 << 16;
        int by0 = y0 << 8,  by1 = y1 << 8;
        float g000 = grid[bx0|by0|z0], g100 = grid[bx1|by0|z0];
        float g010 = grid[bx0|by1|z0], g110 = grid[bx1|by1|z0];
        float g001 = grid[bx0|by0|z1], g101 = grid[bx1|by0|z1];
        float g011 = grid[bx0|by1|z1], g111 = grid[bx1|by1|z1];
        float c00 = g000*(1.f-fx) + g100*fx;
        float c10 = g010*(1.f-fx) + g110*fx;
        float c01 = g001*(1.f-fx) + g101*fx;
        float c11 = g011*(1.f-fx) + g111*fx;
        float c0  = c00*(1.f-fy) + c10*fy;
        float c1  = c01*(1.f-fy) + c11*fy;
        float v   = c0*(1.f-fz) + c1*fz;
        out[1 + (size_t)b * N + n] = v;
        val = v * v;
    }
    #pragma unroll
    for (int off = 32; off > 0; off >>= 1) val += __shfl_down(val, off, 64);
    __shared__ float sm[4];
    int lane = threadIdx.x & 63, wid = threadIdx.x >> 6;
    if (lane == 0) sm[wid] = val;
    __syncthreads();
    if (threadIdx.x == 0)
        atomicAdd(out, 0.5f * (sm[0] + sm[1] + sm[2] + sm[3]));
}

extern "C" void kernel_launch(void* const* d_in, const int* in_sizes, int n_in,
                              void* d_out, int out_size, void* d_ws, size_t ws_size,
                              hipStream_t stream) {
    const float* pose_delta = (const float*)d_in[0];
    const float* pose_init  = (const float*)d_in[1];
    const float* grid       = (const float*)d_in[2];
    const float* limits     = (const float*)d_in[3];
    const float* points     = (const float*)d_in[4];
    float* out = (float*)d_out;

    int B = in_sizes[0] / 6;
    int N = in_sizes[4] / 3;
    long long se3_off = 1 + (long long)B * N;

    const size_t TBL_OFF = 131072;                                  // 128KB
    const size_t needZP = TBL_OFF + (size_t)255 * 65536 * 8;        // ~127.6MB
    float* rt  = (float*)d_ws;
    uint2* tbl = (uint2*)((char*)d_ws + TBL_OFF);

    bool g256 = (in_sizes[2] == (1 << 24));
    int gridX = (N + 255) / 256;

    if (g256 && ws_size >= needZP && B <= 256) {
        pack_pose<<<255 * 65536 / 256, 256, 0, stream>>>(grid, tbl, pose_delta,
                                                         pose_init, out, rt, B, se3_off);
        int nBG = (B + 3) / 4;
        dim3 g(gridX, nBG);
        sdf_zp4<<<g, 256, 0, stream>>>(tbl, limits, points, rt, out + 1, out, N, B);
    } else {
        pose_kernel<<<1, ((B + 63) / 64) * 64, 0, stream>>>(pose_delta, pose_init,
                                                            out, rt, B, se3_off);
        dim3 g(gridX, B);
        sdf_kernel<<<g, 256, 0, stream>>>(grid, limits, points, rt, out, N);
    }
}

// Round 7
// 144.578 us; speedup vs baseline: 1.1047x; 1.1047x over previous
//
#include <hip/hip_runtime.h>
#include <hip/hip_fp16.h>
#include <math.h>

// SDF loss: out = [loss(1), sdf_values(B*N), se3(B*16)]  (float32)
// G fixed at 256: flat grid index = (x<<16)|(y<<8)|z.
// u clamped to <= 254.9999 so x0,y0,z0 <= 254; min(i0+1,255) never binds.
//
// ws layout: [0,4KB) rt | [4KB,128KB) partials | [128KB, +127.5MB) table
// Z-plane table: entry e(x,y,z) = fp16x4 xy-cell corners in plane z:
//   .x = half2( g(x,y,z),   g(x+1,y,z)   )
//   .y = half2( g(x,y+1,z), g(x+1,y+1,z) )
// Sample reads entries z0,z0+1 (16 contiguous B, same 64B line 7/8 of time).
// Model (r3-r6): sdf is L3-line-service bound (~16 TB/s beyond-L2, 1 line per
// sample structurally); pack is HBM bound. NT stores / same-address atomics
// regress (r6). This round: round-5 proven bodies + fused pack+pose launch.

__device__ __forceinline__ void pose_math(const float* __restrict__ pose_delta,
                                          const float* __restrict__ pose_init,
                                          float* __restrict__ out,
                                          float* __restrict__ rt,
                                          int b, long long se3_off)
{
    const float* d = pose_delta + b * 6;
    float ux = d[0], uy = d[1], uz = d[2];
    float wx = d[3], wy = d[4], wz = d[5];
    float th2 = wx*wx + wy*wy + wz*wz;
    float th  = sqrtf(th2);
    float A, Bc, Cc;
    if (th < 1e-6f) {
        A  = 1.0f - th2 * (1.0f/6.0f);
        Bc = 0.5f - th2 * (1.0f/24.0f);
        Cc = (1.0f/6.0f) - th2 * (1.0f/120.0f);
    } else {
        float sn = sinf(th), cs = cosf(th);
        A  = sn / th;
        Bc = (1.0f - cs) / th2;
        Cc = (th - sn) / (th2 * th);
    }
    float K[3][3]  = {{0.f,-wz,wy},{wz,0.f,-wx},{-wy,wx,0.f}};
    float K2[3][3];
    #pragma unroll
    for (int i = 0; i < 3; i++)
        #pragma unroll
        for (int j = 0; j < 3; j++) {
            float s = 0.f;
            #pragma unroll
            for (int k = 0; k < 3; k++) s += K[i][k] * K[k][j];
            K2[i][j] = s;
        }
    float R[3][3], V[3][3];
    #pragma unroll
    for (int i = 0; i < 3; i++)
        #pragma unroll
        for (int j = 0; j < 3; j++) {
            float I = (i == j) ? 1.f : 0.f;
            R[i][j] = I + A  * K[i][j] + Bc * K2[i][j];
            V[i][j] = I + Bc * K[i][j] + Cc * K2[i][j];
        }
    float tt[3];
    #pragma unroll
    for (int i = 0; i < 3; i++)
        tt[i] = V[i][0]*ux + V[i][1]*uy + V[i][2]*uz;

    const float* P = pose_init + b * 16;
    float M[3][4];
    #pragma unroll
    for (int i = 0; i < 3; i++)
        #pragma unroll
        for (int j = 0; j < 4; j++)
            M[i][j] = R[i][0]*P[0*4+j] + R[i][1]*P[1*4+j] + R[i][2]*P[2*4+j] + tt[i]*P[3*4+j];

    float* o = out + se3_off + (long long)b * 16;
    #pragma unroll
    for (int i = 0; i < 3; i++)
        #pragma unroll
        for (int j = 0; j < 4; j++) o[i*4+j] = M[i][j];
    o[12] = P[12]; o[13] = P[13]; o[14] = P[14]; o[15] = P[15];

    float* r = rt + b * 12;
    #pragma unroll
    for (int i = 0; i < 3; i++) {
        r[i*4+0] = M[i][0]; r[i*4+1] = M[i][1];
        r[i*4+2] = M[i][2]; r[i*4+3] = M[i][3];
    }
}

// Fused: z-plane table pack (all blocks) + pose math + loss zero (block 0).
__global__ __launch_bounds__(256)
void pack_pose(const float* __restrict__ g, uint2* __restrict__ tbl,
               const float* __restrict__ pose_delta,
               const float* __restrict__ pose_init,
               float* __restrict__ out, float* __restrict__ rt,
               int B, long long se3_off)
{
    int idx = blockIdx.x * 256 + threadIdx.x;   // x = idx>>16 in [0,254]
    int y = (idx >> 8) & 255;
    int ys = (y < 255) ? 256 : 0;               // y=255 entries never read; avoid OOB
    const float* p = g + idx;                   // x+1 <= 255 always (x <= 254)
    float e00 = p[0],          e10 = p[65536];
    float e01 = p[ys],         e11 = p[65536 + ys];
    uint2 u;
    __half2 h;
    h = __floats2half2_rn(e00, e10); u.x = *(unsigned int*)&h;
    h = __floats2half2_rn(e01, e11); u.y = *(unsigned int*)&h;
    tbl[idx] = u;

    if (blockIdx.x == 0) {
        if (threadIdx.x == 0) out[0] = 0.0f;
        if ((int)threadIdx.x < B)
            pose_math(pose_delta, pose_init, out, rt, threadIdx.x, se3_off);
    }
}

// 4 poses per thread; per sample two 8B loads (z0, z0+1), same 64B line 7/8.
// Regular stores; per-block partial to ws (r6: NT store / atomic regress).
__global__ __launch_bounds__(256)
void sdf_zp4(const uint2* __restrict__ tbl,
             const float* __restrict__ limits,
             const float* __restrict__ points,
             const float* __restrict__ rt,
             float* __restrict__ sdf_out,     // out+1
             float* __restrict__ partials,    // ws+4KB
             int N, int B)
{
    const int bg = blockIdx.y;       // pose group
    const int b0 = bg * 4;
    const int n  = blockIdx.x * 256 + threadIdx.x;

    float M[4][12];
    #pragma unroll
    for (int bb = 0; bb < 4; bb++) {
        int b = min(b0 + bb, B - 1);
        const float* m = rt + b * 12;
        #pragma unroll
        for (int j = 0; j < 12; j++) M[bb][j] = m[j];
    }
    float lo0=limits[0], lo1=limits[1], lo2=limits[2];
    float hi0=limits[3], hi1=limits[4], hi2=limits[5];
    float s0 = 255.0f/(hi0-lo0), s1 = 255.0f/(hi1-lo1), s2 = 255.0f/(hi2-lo2);

    float val = 0.0f;
    if (n < N) {
        float px = points[n*3+0], py = points[n*3+1], pz = points[n*3+2];

        int   idx[4];
        float fx[4], fy[4], fz[4];
        #pragma unroll
        for (int bb = 0; bb < 4; bb++) {
            float x = M[bb][0]*px + M[bb][1]*py + M[bb][2]*pz  + M[bb][3];
            float y = M[bb][4]*px + M[bb][5]*py + M[bb][6]*pz  + M[bb][7];
            float z = M[bb][8]*px + M[bb][9]*py + M[bb][10]*pz + M[bb][11];
            float u0 = fminf(fmaxf((x - lo0) * s0, 0.f), 254.9999f);
            float u1 = fminf(fmaxf((y - lo1) * s1, 0.f), 254.9999f);
            float u2 = fminf(fmaxf((z - lo2) * s2, 0.f), 254.9999f);
            int x0 = (int)u0, y0 = (int)u1, z0 = (int)u2;
            fx[bb] = u0 - (float)x0;
            fy[bb] = u1 - (float)y0;
            fz[bb] = u2 - (float)z0;
            idx[bb] = (x0 << 16) | (y0 << 8) | z0;
        }

        // 8 independent 8B gathers (4 line-pairs) in flight
        uint2 e0[4], e1[4];
        #pragma unroll
        for (int bb = 0; bb < 4; bb++) {
            e0[bb] = tbl[idx[bb]];
            e1[bb] = tbl[idx[bb] + 1];
        }

        #pragma unroll
        for (int bb = 0; bb < 4; bb++) {
            float2 a00 = __half22float2(*(__half2*)&e0[bb].x);  // (e00,e10) @ z0
            float2 a01 = __half22float2(*(__half2*)&e0[bb].y);  // (e01,e11) @ z0
            float2 b00 = __half22float2(*(__half2*)&e1[bb].x);  // @ z1
            float2 b01 = __half22float2(*(__half2*)&e1[bb].y);
            float c0 = a00.x + (a00.y - a00.x) * fx[bb];
            float c1 = a01.x + (a01.y - a01.x) * fx[bb];
            float p0 = c0 + (c1 - c0) * fy[bb];                 // plane z0
            float d0 = b00.x + (b00.y - b00.x) * fx[bb];
            float d1 = b01.x + (b01.y - b01.x) * fx[bb];
            float p1 = d0 + (d1 - d0) * fy[bb];                 // plane z1
            float v  = p0 + (p1 - p0) * fz[bb];
            if (b0 + bb < B) {
                sdf_out[(size_t)(b0 + bb) * N + n] = v;
                val += v * v;
            }
        }
    }

    #pragma unroll
    for (int off = 32; off > 0; off >>= 1) val += __shfl_down(val, off, 64);
    __shared__ float sm[4];
    int lane = threadIdx.x & 63, wid = threadIdx.x >> 6;
    if (lane == 0) sm[wid] = val;
    __syncthreads();
    if (threadIdx.x == 0)
        partials[(size_t)bg * gridDim.x + blockIdx.x] = sm[0] + sm[1] + sm[2] + sm[3];
}

__global__ __launch_bounds__(1024)
void reduce_kernel(const float* __restrict__ partials, int n, float* __restrict__ out)
{
    float s = 0.f;
    for (int i = threadIdx.x; i < n; i += 1024) s += partials[i];
    #pragma unroll
    for (int off = 32; off > 0; off >>= 1) s += __shfl_down(s, off, 64);
    __shared__ float sm[16];
    int lane = threadIdx.x & 63, wid = threadIdx.x >> 6;
    if (lane == 0) sm[wid] = s;
    __syncthreads();
    if (threadIdx.x == 0) {
        float t = 0.f;
        #pragma unroll
        for (int i = 0; i < 16; i++) t += sm[i];
        out[0] = 0.5f * t;
    }
}

// ---------------- Fallback path (non-256 grid or tiny ws) ----------------
__global__ void pose_kernel(const float* __restrict__ pose_delta,
                            const float* __restrict__ pose_init,
                            float* __restrict__ out,
                            float* __restrict__ rt,
                            int B, long long se3_off)
{
    int b = blockIdx.x * blockDim.x + threadIdx.x;
    if (b == 0) out[0] = 0.0f;
    if (b >= B) return;
    pose_math(pose_delta, pose_init, out, rt, b, se3_off);
}

__global__ __launch_bounds__(256)
void sdf_kernel(const float* __restrict__ grid,
                const float* __restrict__ limits,
                const float* __restrict__ points,
                const float* __restrict__ rt,
                float* __restrict__ out, int N)
{
    const int b = blockIdx.y;
    const int n = blockIdx.x * 256 + threadIdx.x;
    const float* m = rt + b * 12;
    float m00=m[0], m01=m[1], m02=m[2],  m03=m[3];
    float m10=m[4], m11=m[5], m12=m[6],  m13=m[7];
    float m20=m[8], m21=m[9], m22=m[10], m23=m[11];
    float lo0=limits[0], lo1=limits[1], lo2=limits[2];
    float hi0=limits[3], hi1=limits[4], hi2=limits[5];
    float s0 = 255.0f/(hi0-lo0), s1 = 255.0f/(hi1-lo1), s2 = 255.0f/(hi2-lo2);

    float val = 0.0f;
    if (n < N) {
        float px = points[n*3+0], py = points[n*3+1], pz = points[n*3+2];
        float x = m00*px + m01*py + m02*pz + m03;
        float y = m10*px + m11*py + m12*pz + m13;
        float z = m20*px + m21*py + m22*pz + m23;
        float u0 = fminf(fmaxf((x - lo0) * s0, 0.f), 254.9999f);
        float u1 = fminf(fmaxf((y - lo1) * s1, 0.f), 254.9999f);
        float u2 = fminf(fmaxf((z - lo2) * s2, 0.f), 254.9999f);
        int x0 = (int)u0, y0 = (int)u1, z0 = (int)u2;
        float fx = u0 - (float)x0, fy = u1 - (float)y0, fz = u2 - (float)z0;
        int x1 = x0 + 1, y1 = y0 + 1, z1 = z0 + 1;
        int bx0 = x0 << 16, bx1 = x1 << 16;
        int by0 = y0 << 8,  by1 = y1 << 8;
        float g000 = grid[bx0|by0|z0], g100 = grid[bx1|by0|z0];
        float g010 = grid[bx0|by1|z0], g110 = grid[bx1|by1|z0];
        float g001 = grid[bx0|by0|z1], g101 = grid[bx1|by0|z1];
        float g011 = grid[bx0|by1|z1], g111 = grid[bx1|by1|z1];
        float c00 = g000*(1.f-fx) + g100*fx;
        float c10 = g010*(1.f-fx) + g110*fx;
        float c01 = g001*(1.f-fx) + g101*fx;
        float c11 = g011*(1.f-fx) + g111*fx;
        float c0  = c00*(1.f-fy) + c10*fy;
        float c1  = c01*(1.f-fy) + c11*fy;
        float v   = c0*(1.f-fz) + c1*fz;
        out[1 + (size_t)b * N + n] = v;
        val = v * v;
    }
    #pragma unroll
    for (int off = 32; off > 0; off >>= 1) val += __shfl_down(val, off, 64);
    __shared__ float sm[4];
    int lane = threadIdx.x & 63, wid = threadIdx.x >> 6;
    if (lane == 0) sm[wid] = val;
    __syncthreads();
    if (threadIdx.x == 0)
        atomicAdd(out, 0.5f * (sm[0] + sm[1] + sm[2] + sm[3]));
}

extern "C" void kernel_launch(void* const* d_in, const int* in_sizes, int n_in,
                              void* d_out, int out_size, void* d_ws, size_t ws_size,
                              hipStream_t stream) {
    const float* pose_delta = (const float*)d_in[0];
    const float* pose_init  = (const float*)d_in[1];
    const float* grid       = (const float*)d_in[2];
    const float* limits     = (const float*)d_in[3];
    const float* points     = (const float*)d_in[4];
    float* out = (float*)d_out;

    int B = in_sizes[0] / 6;
    int N = in_sizes[4] / 3;
    long long se3_off = 1 + (long long)B * N;

    const size_t TBL_OFF = 131072;                                  // 128KB
    const size_t needZP = TBL_OFF + (size_t)255 * 65536 * 8;        // ~127.6MB
    float* rt       = (float*)d_ws;
    float* partials = (float*)((char*)d_ws + 4096);
    uint2* tbl      = (uint2*)((char*)d_ws + TBL_OFF);

    bool g256 = (in_sizes[2] == (1 << 24));
    int gridX = (N + 255) / 256;
    int nBG   = (B + 3) / 4;
    // partials region is 124KB -> holds up to ~31k floats; need gridX*nBG
    bool partials_fit = (size_t)gridX * nBG * sizeof(float) <= (TBL_OFF - 4096);

    if (g256 && ws_size >= needZP && B <= 256 && partials_fit) {
        pack_pose<<<255 * 65536 / 256, 256, 0, stream>>>(grid, tbl, pose_delta,
                                                         pose_init, out, rt, B, se3_off);
        dim3 g(gridX, nBG);
        sdf_zp4<<<g, 256, 0, stream>>>(tbl, limits, points, rt, out + 1, partials, N, B);
        reduce_kernel<<<1, 1024, 0, stream>>>(partials, nBG * gridX, out);
    } else {
        pose_kernel<<<1, ((B + 63) / 64) * 64, 0, stream>>>(pose_delta, pose_init,
                                                            out, rt, B, se3_off);
        dim3 g(gridX, B);
        sdf_kernel<<<g, 256, 0, stream>>>(grid, limits, points, rt, out, N);
    }
}